// Round 4
// baseline (298.911 us; speedup 1.0000x reference)
//
#include <hip/hip_runtime.h>
#include <stdint.h>

typedef unsigned int u32;
typedef unsigned long long u64;

#define N8   130560   // (2176/8)*(3840/8)   = 272*480
#define N16  32640    // (2176/16)*(3840/16) = 136*240
#define N32  8160     // (2176/32)*(3840/32) = 68*120
#define NTOT 171360
#define NTOT4 42840   // NTOT/4
#define TOPK 1000
#define NWORDS 16
#define NBINS 4096
#define BUCKET_SCALE 682.0f
#define LIST_CAP 2048
#define OUT_ELEMS 15000
#define NBLK 168           // ceil(NTOT4/256); <= 256 CUs -> all blocks co-resident
#define IOU_TASKS (TOPK * NWORDS)   // 16000
#define NMS_CACHE 256      // suppression rows staged in LDS (global fallback past this)

// workspace layout (bytes)
#define OFF_HIST   0        // u32[4096]
#define OFF_META   16384    // u32[16]: 1=listCnt, 8..12=grid-barrier counters
#define OFF_NZ     16448    // u64[16]
#define MEMSET_BYTES 16576
#define OFF_KEEP   16576    // u64[16] (plain-stored by block 0; no memset needed)
#define OFF_BOXES  16704    // f32[4000] (16B aligned)
#define OFF_SCORES 32704    // f32[1000]
#define OFF_KPS    36704    // f32[10000]
#define OFF_LIST   76704    // u64[2048]
#define OFF_MASK   93088    // u64[1000*16]

__device__ __forceinline__ u32 bucket_of(float x) {
  u32 b = (u32)(x * BUCKET_SCALE);
  return b > (NBINS - 1) ? (NBINS - 1) : b;
}

__device__ __forceinline__ float4 load_logit4(int v, const float* s8, const float* s16,
                                              const float* s32) {
  int e = v * 4;
  if (e < N8) return ((const float4*)s8)[v];
  if (e < N8 + N16) return ((const float4*)s16)[v - N8 / 4];
  return ((const float4*)s32)[v - (N8 + N16) / 4];
}

__device__ __forceinline__ bool iou_gt04(float4 a, float4 b) {
#pragma clang fp contract(off)
  float areaA = (a.z - a.x) * (a.w - a.y);
  float areaB = (b.z - b.x) * (b.w - b.y);
  float ltx = fmaxf(a.x, b.x);
  float lty = fmaxf(a.y, b.y);
  float rbx = fminf(a.z, b.z);
  float rby = fminf(a.w, b.w);
  float wx = rbx - ltx; wx = wx > 0.0f ? wx : 0.0f;
  float wy = rby - lty; wy = wy > 0.0f ? wy : 0.0f;
  float inter = wx * wy;
  float un = areaA + areaB - inter;
  un = un > 1e-9f ? un : 1e-9f;
  return (inter / un) > 0.4f;
}

__device__ __forceinline__ u64 valid_word(int w, u32 vcnt) {
  int lo = w * 64;
  if ((int)vcnt >= lo + 64) return ~0ull;
  if ((int)vcnt <= lo) return 0ull;
  return (1ull << (vcnt - (u32)lo)) - 1ull;
}

// Device-scope grid barrier. All NBLK blocks are co-resident (168 <= 256 CUs, 36KB LDS,
// 256 thr). Release: every thread fences (wbl2) before arrive; acquire: spin on
// agent-scope atomic, then fence (inv) so subsequent PLAIN loads see other XCDs' writes.
// Counters live in the memset region -> re-zeroed before every timed launch.
__device__ __forceinline__ void gbar(u32* ctr) {
  __threadfence();
  __syncthreads();
  if (threadIdx.x == 0) {
    __hip_atomic_fetch_add(ctr, 1u, __ATOMIC_ACQ_REL, __HIP_MEMORY_SCOPE_AGENT);
    while (__hip_atomic_load(ctr, __ATOMIC_ACQUIRE, __HIP_MEMORY_SCOPE_AGENT) < (u32)NBLK)
      __builtin_amdgcn_s_sleep(2);
    __threadfence();
  }
  __syncthreads();
}

__global__ void __launch_bounds__(256) k_mono(
    const float* __restrict__ s8, const float* __restrict__ s16, const float* __restrict__ s32,
    const float* __restrict__ bb8, const float* __restrict__ kp8,
    const float* __restrict__ bb16, const float* __restrict__ kp16,
    const float* __restrict__ bb32, const float* __restrict__ kp32,
    u32* hist, u32* meta, u64* nzWords, u64* keepWords,
    float* sBoxes, float* sScores, float* sKps,
    u64* list, u64* mask, float* out) {
  // phase-overlaid LDS: B(findB)=17408, D(keys)=16384, E(boxes)=16000, F(rows+cache)=36864
  __shared__ __align__(16) char smem[36864];
  __shared__ u32 sB;
  __shared__ u32 sPc[16], sOff17[17];

  const int t = threadIdx.x;
  const int blk = blockIdx.x;
  const int gid = blk * 256 + t;

  // ---- Phase A: histogram of positive logits (scores stay in registers) ----
  float4 x = make_float4(-1.f, -1.f, -1.f, -1.f);
  const bool have = (gid < NTOT4);
  if (have) {
    x = load_logit4(gid, s8, s16, s32);
    if (x.x > 0.0f) atomicAdd(&hist[bucket_of(x.x)], 1u);
    if (x.y > 0.0f) atomicAdd(&hist[bucket_of(x.y)], 1u);
    if (x.z > 0.0f) atomicAdd(&hist[bucket_of(x.z)], 1u);
    if (x.w > 0.0f) atomicAdd(&hist[bucket_of(x.w)], 1u);
  }
  gbar(&meta[8]);

  // ---- Phase B: findB, computed redundantly per block (no extra barrier) ----
  // B = max bucket with count(>=B) >= TOPK; 0 if fewer than TOPK positives.
  {
    u32* hloc = (u32*)smem;             // 4096 u32
    u32* csum = (u32*)(smem + 16384);   // 256 u32
    u32 sum = 0;
    int base = t * 16;
#pragma unroll
    for (int k = 0; k < 16; ++k) { u32 v = hist[base + k]; hloc[base + k] = v; sum += v; }
    csum[t] = sum;
    __syncthreads();
    for (int off = 1; off < 256; off <<= 1) {   // inclusive suffix scan
      u32 add = (t + off < 256) ? csum[t + off] : 0u;
      __syncthreads();
      csum[t] += add;
      __syncthreads();
    }
    if (t == 0 && csum[0] < TOPK) sB = 0;
    u32 above = (t < 255) ? csum[t + 1] : 0u;
    if (csum[t] >= TOPK && above < TOPK) {      // exactly one thread
      u32 cum = above, Bv = (u32)(t * 16);
      for (int b = t * 16 + 15; b >= t * 16; --b) {
        cum += hloc[b];
        if (cum >= TOPK) { Bv = (u32)b; break; }
      }
      sB = Bv;
    }
    __syncthreads();
  }
  const u32 B = sB;

  // ---- Phase C: compact candidates (bucket >= B) as (logit_bits<<32)|~idx ----
  if (have) {
    float c[4] = {x.x, x.y, x.z, x.w};
#pragma unroll
    for (int j = 0; j < 4; ++j) {
      float xx = c[j];
      if (xx > 0.0f && bucket_of(xx) >= B) {
        u32 pos = atomicAdd(&meta[1], 1u);
        if (pos < LIST_CAP) {
          u32 idx = (u32)(gid * 4 + j);
          list[pos] = ((u64)__float_as_uint(xx) << 32) | (u64)(~idx);
        }
      }
    }
  }
  gbar(&meta[9]);

  u32 cnt = meta[1];
  if (cnt > LIST_CAP) cnt = LIST_CAP;

  // ---- Phase D: O(n^2) exact rank (desc key = stable top-k) + decode, blocks 0..7 ----
  if (blk < 8) {
    u64* keys = (u64*)smem;
    for (int j = t; j < LIST_CAP; j += 256) keys[j] = (j < (int)cnt) ? list[j] : 0ull;
    __syncthreads();
    int tid = blk * 256 + t;
    if (tid < (int)cnt) {
      u64 my = keys[tid];
      int rank = 0, j = 0;
      for (; j + 4 <= (int)cnt; j += 4)
        rank += (keys[j] > my) + (keys[j + 1] > my) + (keys[j + 2] > my) + (keys[j + 3] > my);
      for (; j < (int)cnt; ++j) rank += (keys[j] > my);
      if (rank < TOPK) {
        float lx = __uint_as_float((u32)(my >> 32));
        float sc = (float)(1.0 / (1.0 + exp(-(double)lx)));   // sigmoid in f64, round once
        u32 idx = ~((u32)my);
        float4 box;
        float kv[10];
        int p, xq, yq;
        float st;
        const float *bb, *kp;
        if (idx < N8) {
          st = 8.f;  p = (int)idx;              xq = p % 480; yq = p / 480; bb = bb8;  kp = kp8;
        } else if (idx < N8 + N16) {
          st = 16.f; p = (int)idx - N8;         xq = p % 240; yq = p / 240; bb = bb16; kp = kp16;
        } else {
          st = 32.f; p = (int)idx - (N8 + N16); xq = p % 120; yq = p / 120; bb = bb32; kp = kp32;
        }
        float cx = (float)xq * st, cy = (float)yq * st;
        {
#pragma clang fp contract(off)
          float d0 = bb[4 * p + 0] * st;
          float d1 = bb[4 * p + 1] * st;
          float d2 = bb[4 * p + 2] * st;
          float d3 = bb[4 * p + 3] * st;
          box.x = cx - d0; box.y = cy - d1; box.z = cx + d2; box.w = cy + d3;
          for (int q = 0; q < 10; ++q)
            kv[q] = kp[10 * p + q] * st + ((q & 1) ? cy : cx);
        }
        ((float4*)sBoxes)[rank] = box;
        sScores[rank] = sc;
        for (int q = 0; q < 10; ++q) sKps[10 * rank + q] = kv[q];
      }
    } else if (tid < TOPK) {   // unfilled rows: zero (invalid via vcnt)
      ((float4*)sBoxes)[tid] = make_float4(0.f, 0.f, 0.f, 0.f);
      sScores[tid] = 0.f;
      for (int q = 0; q < 10; ++q) sKps[10 * tid + q] = 0.f;
    }
  }
  gbar(&meta[10]);

  // ---- Phase E: suppression bitmask + nz bitmap, blocks 0..62 ----
  if (blk < 63) {
    float4* boxes = (float4*)smem;
    for (int r = t; r < TOPK; r += 256) boxes[r] = ((const float4*)sBoxes)[r];
    __syncthreads();
    int task = blk * 256 + t;
    if (task < IOU_TASKS) {
      int i = task >> 4, w = task & 15;
      float4 a = boxes[i];
      u64 bits = 0;
      int bse = w * 64;
      int j0 = bse > (i + 1) ? bse : (i + 1);
      int j1 = (bse + 64) < TOPK ? (bse + 64) : TOPK;
      for (int j = j0; j < j1; ++j)
        if (iou_gt04(a, boxes[j])) bits |= 1ull << (j - bse);
      mask[(u64)i * NWORDS + w] = bits;
      if (bits) atomicOr(&nzWords[i >> 6], 1ull << (i & 63));
    }
  }
  gbar(&meta[11]);

  // ---- Phase F: exact greedy NMS over nonzero-mask rows only (block 0) ----
  // Rows with empty suppression sets can't change the removed set -> skipping is exact.
  const u32 vcnt = cnt < TOPK ? cnt : TOPK;
  if (blk == 0) {
    u32* rows = (u32*)smem;             // up to 1000 row ids (4 KB)
    u64* cache = (u64*)(smem + 4096);   // NMS_CACHE x 16 u64 (32 KB)
    u64 nzv = 0;
    if (t < NWORDS) {
      nzv = nzWords[t] & valid_word(t, vcnt);
      sPc[t] = (u32)__popcll(nzv);
    }
    __syncthreads();
    if (t == 0) {
      u32 o = 0;
      for (int w = 0; w < NWORDS; ++w) { sOff17[w] = o; o += sPc[w]; }
      sOff17[16] = o;
    }
    __syncthreads();
    if (t < NWORDS) {           // expand to ascending row list
      u64 m = nzv;
      u32 o = sOff17[t];
      while (m) { int b = __builtin_ctzll(m); m &= m - 1; rows[o++] = (u32)(t * 64 + b); }
    }
    __syncthreads();
    const int S = (int)sOff17[16];
    for (int s = t; s < S && s < NMS_CACHE; s += 256) {  // parallel mask prefetch -> LDS
      u32 row = rows[s];
#pragma unroll
      for (int w = 0; w < NWORDS; ++w) cache[s * NWORDS + w] = mask[(u64)row * NWORDS + w];
    }
    __syncthreads();
    if (t < 64) {               // serial greedy chain, LDS-fed
      u64 remv = 0;             // lane<16 owns removed-word `lane`
      for (int s = 0; s < S; ++s) {
        u32 row = rows[s];
        int c = (int)(row >> 6), b = (int)(row & 63);
        u64 remc = __shfl(remv, c);
        if (!((remc >> b) & 1ull)) {
          u64 m = 0;
          if (t < NWORDS)
            m = (s < NMS_CACHE) ? cache[s * NWORDS + t] : mask[(u64)row * NWORDS + t];
          remv |= m;
        }
      }
      if (t < NWORDS) keepWords[t] = valid_word(t, vcnt) & ~remv;
    }
  }
  gbar(&meta[12]);

  // ---- Phase G: finalize in parallel: [boxes 4000 | scores 1000 | kps 10000] ----
  if (gid < OUT_ELEMS) {
    int o = gid;
    int row; float v;
    if (o < 4000)      { row = o >> 2;   v = sBoxes[o]; }
    else if (o < 5000) { row = o - 4000; v = sScores[row]; }
    else               { int q = o - 5000; row = q / 10; v = sKps[q]; }
    u64 kw = keepWords[row >> 6];
    out[o] = ((kw >> (row & 63)) & 1ull) ? v : 0.0f;
  }
}

extern "C" void kernel_launch(void* const* d_in, const int* in_sizes, int n_in,
                              void* d_out, int out_size, void* d_ws, size_t ws_size,
                              hipStream_t stream) {
  const float* s8   = (const float*)d_in[1];
  const float* bb8  = (const float*)d_in[2];
  const float* kp8  = (const float*)d_in[3];
  const float* s16  = (const float*)d_in[4];
  const float* bb16 = (const float*)d_in[5];
  const float* kp16 = (const float*)d_in[6];
  const float* s32  = (const float*)d_in[7];
  const float* bb32 = (const float*)d_in[8];
  const float* kp32 = (const float*)d_in[9];

  char* ws = (char*)d_ws;
  u32* hist       = (u32*)(ws + OFF_HIST);
  u32* meta       = (u32*)(ws + OFF_META);
  u64* nzWords    = (u64*)(ws + OFF_NZ);
  u64* keepWords  = (u64*)(ws + OFF_KEEP);
  float* sBoxes   = (float*)(ws + OFF_BOXES);
  float* sScores  = (float*)(ws + OFF_SCORES);
  float* sKps     = (float*)(ws + OFF_KPS);
  u64* list       = (u64*)(ws + OFF_LIST);
  u64* mask       = (u64*)(ws + OFF_MASK);

  hipMemsetAsync(ws, 0, MEMSET_BYTES, stream);
  k_mono<<<NBLK, 256, 0, stream>>>(s8, s16, s32, bb8, kp8, bb16, kp16, bb32, kp32,
                                   hist, meta, nzWords, keepWords,
                                   sBoxes, sScores, sKps, list, mask, (float*)d_out);
}

// Round 5
// 235.294 us; speedup vs baseline: 1.2704x; 1.2704x over previous
//
#include <hip/hip_runtime.h>
#include <stdint.h>

typedef unsigned int u32;
typedef unsigned long long u64;

#define N8   130560   // (2176/8)*(3840/8)   = 272*480
#define N16  32640    // (2176/16)*(3840/16) = 136*240
#define N32  8160     // (2176/32)*(3840/32) = 68*120
#define NTOT 171360
#define NTOT4 42840   // NTOT/4
#define TOPK 1000
#define NWORDS 16
#define NBINS 4096
#define BUCKET_SCALE 682.0f
#define LIST_CAP 2048
#define OUT_ELEMS 15000
#define NBLK 168           // ceil(NTOT4/256); 37KB LDS/256thr -> >=4 blocks/CU capacity, co-resident
#define IOU_TASKS (TOPK * NWORDS)   // 16000
#define IOU_BLKS 63
#define NMS_CACHE 256      // suppression rows staged in LDS (global fallback past this)

// workspace layout (bytes)
#define OFF_HIST 0          // u32[4096]
#define OFF_META 16384      // u32[64]: [1]=listCnt, [4]=doneE; gbar ctrs at [16],[32],[48] (own lines)
#define OFF_NZ   16640      // u64[16]
#define MEMSET_BYTES 16768
#define OFF_LIST 16768      // u64[2048]
#define OFF_MASK 33152      // u64[16*1000], TRANSPOSED: mask[w*1000+i]

__device__ __forceinline__ u32 bucket_of(float x) {
  u32 b = (u32)(x * BUCKET_SCALE);
  return b > (NBINS - 1) ? (NBINS - 1) : b;
}

__device__ __forceinline__ float4 load_logit4(int v, const float* s8, const float* s16,
                                              const float* s32) {
  int e = v * 4;
  if (e < N8) return ((const float4*)s8)[v];
  if (e < N8 + N16) return ((const float4*)s16)[v - N8 / 4];
  return ((const float4*)s32)[v - (N8 + N16) / 4];
}

__device__ __forceinline__ bool iou_gt04(float4 a, float4 b) {
#pragma clang fp contract(off)
  float areaA = (a.z - a.x) * (a.w - a.y);
  float areaB = (b.z - b.x) * (b.w - b.y);
  float ltx = fmaxf(a.x, b.x);
  float lty = fmaxf(a.y, b.y);
  float rbx = fminf(a.z, b.z);
  float rby = fminf(a.w, b.w);
  float wx = rbx - ltx; wx = wx > 0.0f ? wx : 0.0f;
  float wy = rby - lty; wy = wy > 0.0f ? wy : 0.0f;
  float inter = wx * wy;
  float un = areaA + areaB - inter;
  un = un > 1e-9f ? un : 1e-9f;
  return (inter / un) > 0.4f;
}

__device__ __forceinline__ u64 valid_word(int w, u32 vcnt) {
  int lo = w * 64;
  if ((int)vcnt >= lo + 64) return ~0ull;
  if ((int)vcnt <= lo) return 0ull;
  return (1ull << (vcnt - (u32)lo)) - 1ull;
}

// Grid barrier, fences in thread 0 ONLY (ROCm cooperative-groups grid.sync pattern).
// __syncthreads drains all waves' vmcnt to L2 (compiler-guaranteed); t0's release
// __threadfence (buffer_wbl2) then publishes the whole local L2; t0's acquire
// __threadfence (buffer_inv) invalidates this CU's L1 + local L2, and the trailing
// __syncthreads orders every other thread's plain loads after it. R4's all-thread
// fencing (430k cache-maintenance ops) was the 167us regression.
__device__ __forceinline__ void gbar(u32* ctr) {
  __syncthreads();
  if (threadIdx.x == 0) {
    __threadfence();   // release
    __hip_atomic_fetch_add(ctr, 1u, __ATOMIC_RELAXED, __HIP_MEMORY_SCOPE_AGENT);
    while (__hip_atomic_load(ctr, __ATOMIC_RELAXED, __HIP_MEMORY_SCOPE_AGENT) < (u32)NBLK)
      __builtin_amdgcn_s_sleep(4);
    __threadfence();   // acquire
  }
  __syncthreads();
}

__global__ void __launch_bounds__(256) k_mono(
    const float* __restrict__ s8, const float* __restrict__ s16, const float* __restrict__ s32,
    const float* __restrict__ bb8, const float* __restrict__ kp8,
    const float* __restrict__ bb16, const float* __restrict__ kp16,
    const float* __restrict__ bb32, const float* __restrict__ kp32,
    u32* hist, u32* meta, u64* nzWords, u64* list, u64* mask, float* out) {
  // phase-overlaid LDS: B(hloc+csum)=17.4K, D(keys)=16K, E(boxes)=16K, F(rows+cache)=36.9K
  __shared__ __align__(16) char smem[36864];
  __shared__ u32 sB;
  __shared__ int isLast;
  __shared__ u32 sPc[16], sOff17[17];
  __shared__ u64 sRem[NWORDS];

  const int t = threadIdx.x;
  const int blk = blockIdx.x;
  const int gid = blk * 256 + t;

  // ---- Phase A: histogram of positive logits (scores stay in registers) ----
  float4 x = make_float4(-1.f, -1.f, -1.f, -1.f);
  const bool have = (gid < NTOT4);
  if (have) {
    x = load_logit4(gid, s8, s16, s32);
    if (x.x > 0.0f) atomicAdd(&hist[bucket_of(x.x)], 1u);
    if (x.y > 0.0f) atomicAdd(&hist[bucket_of(x.y)], 1u);
    if (x.z > 0.0f) atomicAdd(&hist[bucket_of(x.z)], 1u);
    if (x.w > 0.0f) atomicAdd(&hist[bucket_of(x.w)], 1u);
  }
  gbar(&meta[16]);

  // ---- Phase B: findB, redundant per block (no extra barrier) ----
  // B = max bucket with count(>=B) >= TOPK; 0 if fewer than TOPK positives.
  {
    u32* hloc = (u32*)smem;             // hloc[b] = hist[b], 4096 u32
    u32* csum = (u32*)(smem + 16384);   // 256 u32
#pragma unroll
    for (int k = 0; k < 16; ++k) hloc[k * 256 + t] = hist[k * 256 + t];  // coalesced
    __syncthreads();
    u32 sum = 0;
    int base = t * 16;
#pragma unroll
    for (int k = 0; k < 16; ++k) sum += hloc[base + k];
    csum[t] = sum;
    __syncthreads();
    for (int off = 1; off < 256; off <<= 1) {   // inclusive suffix scan
      u32 add = (t + off < 256) ? csum[t + off] : 0u;
      __syncthreads();
      csum[t] += add;
      __syncthreads();
    }
    if (t == 0 && csum[0] < TOPK) sB = 0;
    u32 above = (t < 255) ? csum[t + 1] : 0u;
    if (csum[t] >= TOPK && above < TOPK) {      // exactly one thread
      u32 cum = above, Bv = (u32)(t * 16);
      for (int b = t * 16 + 15; b >= t * 16; --b) {
        cum += hloc[b];
        if (cum >= TOPK) { Bv = (u32)b; break; }
      }
      sB = Bv;
    }
    __syncthreads();
  }
  const u32 B = sB;

  // ---- Phase C: compact candidates (bucket >= B) as (logit_bits<<32)|~idx ----
  if (have) {
    float c[4] = {x.x, x.y, x.z, x.w};
#pragma unroll
    for (int j = 0; j < 4; ++j) {
      float xx = c[j];
      if (xx > 0.0f && bucket_of(xx) >= B) {
        u32 pos = atomicAdd(&meta[1], 1u);    // wave-coalesced by compiler (m20)
        if (pos < LIST_CAP) {
          u32 idx = (u32)(gid * 4 + j);
          list[pos] = ((u64)__float_as_uint(xx) << 32) | (u64)(~idx);
        }
      }
    }
  }
  gbar(&meta[32]);

  u32 cnt = meta[1];
  if (cnt > LIST_CAP) cnt = LIST_CAP;
  const u32 vcnt = cnt < TOPK ? cnt : TOPK;   // all selected have logit>0 => valid

  // ---- Phase D: O(n^2) exact rank (desc key = stable top-k) + decode -> out, blocks 0..7 ----
  // out layout: [boxes 4000 | scores 1000 | kps 10000]; rows [cnt,1000) zeroed here.
  if (blk < 8) {
    u64* keys = (u64*)smem;
    for (int j = t; j < LIST_CAP; j += 256) keys[j] = (j < (int)cnt) ? list[j] : 0ull;
    __syncthreads();
    int tid = blk * 256 + t;
    if (tid < (int)cnt) {
      u64 my = keys[tid];
      int rank = 0, j = 0;
      for (; j + 4 <= (int)cnt; j += 4)
        rank += (keys[j] > my) + (keys[j + 1] > my) + (keys[j + 2] > my) + (keys[j + 3] > my);
      for (; j < (int)cnt; ++j) rank += (keys[j] > my);
      if (rank < TOPK) {
        float lx = __uint_as_float((u32)(my >> 32));
        float sc = (float)(1.0 / (1.0 + exp(-(double)lx)));   // sigmoid in f64, round once
        u32 idx = ~((u32)my);
        float4 box;
        float kv[10];
        int p, xq, yq;
        float st;
        const float *bb, *kp;
        if (idx < N8) {
          st = 8.f;  p = (int)idx;              xq = p % 480; yq = p / 480; bb = bb8;  kp = kp8;
        } else if (idx < N8 + N16) {
          st = 16.f; p = (int)idx - N8;         xq = p % 240; yq = p / 240; bb = bb16; kp = kp16;
        } else {
          st = 32.f; p = (int)idx - (N8 + N16); xq = p % 120; yq = p / 120; bb = bb32; kp = kp32;
        }
        float cx = (float)xq * st, cy = (float)yq * st;
        {
#pragma clang fp contract(off)
          float d0 = bb[4 * p + 0] * st;
          float d1 = bb[4 * p + 1] * st;
          float d2 = bb[4 * p + 2] * st;
          float d3 = bb[4 * p + 3] * st;
          box.x = cx - d0; box.y = cy - d1; box.z = cx + d2; box.w = cy + d3;
          for (int q = 0; q < 10; ++q)
            kv[q] = kp[10 * p + q] * st + ((q & 1) ? cy : cx);
        }
        ((float4*)out)[rank] = box;
        out[4000 + rank] = sc;
        for (int q = 0; q < 10; ++q) out[5000 + 10 * rank + q] = kv[q];
      }
    } else if (tid < TOPK) {   // unfilled rows: zero
      ((float4*)out)[tid] = make_float4(0.f, 0.f, 0.f, 0.f);
      out[4000 + tid] = 0.f;
      for (int q = 0; q < 10; ++q) out[5000 + 10 * tid + q] = 0.f;
    }
  }
  gbar(&meta[48]);

  // ---- Phase E: suppression bitmask + nz bitmap, blocks 0..62 ----
  if (blk < IOU_BLKS) {
    float4* boxes = (float4*)smem;
    for (int r = t; r < TOPK; r += 256) boxes[r] = ((const float4*)out)[r];
    __syncthreads();
    int task = blk * 256 + t;
    if (task < IOU_TASKS) {
      int w = task / 1000;          // 0..15  (wave-mostly-uniform)
      int i = task - w * 1000;      // 0..999 (consecutive per lane -> coalesced)
      float4 a = boxes[i];
      int bse = w * 64;
      int jend = (bse + 64) < TOPK ? (bse + 64) : TOPK;
      u64 bits = 0;
      for (int j = bse; j < jend; ++j)          // boxes[j] is wave-broadcast
        if (j > i && iou_gt04(a, boxes[j])) bits |= 1ull << (j - bse);
      mask[(u64)w * 1000 + i] = bits;           // coalesced (transposed layout)
      if (bits) atomicOr(&nzWords[i >> 6], 1ull << (i & 63));
    }
    // last-arriver of the 63 IOU blocks runs NMS + suppressed-row zeroing
    __syncthreads();
    if (t == 0) {
      __threadfence();   // release this block's mask/nz writes
      isLast = (__hip_atomic_fetch_add(&meta[4], 1u, __ATOMIC_RELAXED,
                                       __HIP_MEMORY_SCOPE_AGENT) == (u32)(IOU_BLKS - 1));
      if (isLast) __threadfence();   // acquire all blocks' writes
    }
    __syncthreads();
    if (!isLast) return;

    // ---- Phase F: exact greedy NMS over nonzero-mask rows only ----
    // Rows with empty suppression sets can't change the removed set -> skipping is exact.
    u32* rows = (u32*)smem;             // up to 1000 row ids (4 KB)
    u64* cache = (u64*)(smem + 4096);   // NMS_CACHE x 16 u64 (32 KB)
    u64 nzv = 0;
    if (t < NWORDS) {
      nzv = nzWords[t] & valid_word(t, vcnt);
      sPc[t] = (u32)__popcll(nzv);
    }
    __syncthreads();
    if (t == 0) {
      u32 o = 0;
      for (int w = 0; w < NWORDS; ++w) { sOff17[w] = o; o += sPc[w]; }
      sOff17[16] = o;
    }
    __syncthreads();
    if (t < NWORDS) {           // expand to ascending row list
      u64 m = nzv;
      u32 o = sOff17[t];
      while (m) { int b = __builtin_ctzll(m); m &= m - 1; rows[o++] = (u32)(t * 64 + b); }
    }
    __syncthreads();
    const int S = (int)sOff17[16];
    const int Sc = S < NMS_CACHE ? S : NMS_CACHE;
    for (int idx = t; idx < Sc * NWORDS; idx += 256) {   // parallel mask prefetch -> LDS
      int s = idx >> 4, w = idx & 15;
      cache[s * NWORDS + w] = mask[(u64)w * 1000 + rows[s]];
    }
    __syncthreads();
    if (t < 64) {               // serial greedy chain, LDS-fed; lane<16 owns word `lane`
      u64 remv = 0;
      for (int s = 0; s < S; ++s) {
        u32 row = rows[s];
        int c = (int)(row >> 6), b = (int)(row & 63);
        u64 remc = __shfl(remv, c);
        if (!((remc >> b) & 1ull)) {   // row still alive -> apply its suppression row
          u64 m = 0;
          if (t < NWORDS)
            m = (s < NMS_CACHE) ? cache[s * NWORDS + t] : mask[(u64)t * 1000 + row];
          remv |= m;
        }
      }
      if (t < NWORDS) sRem[t] = valid_word(t, vcnt) & remv;   // rows to zero
    }
    __syncthreads();

    // ---- zero suppressed rows in out (typically few) ----
    for (int r = t; r < TOPK; r += 256) {
      if ((sRem[r >> 6] >> (r & 63)) & 1ull) {
        ((float4*)out)[r] = make_float4(0.f, 0.f, 0.f, 0.f);
        out[4000 + r] = 0.f;
        for (int q = 0; q < 10; ++q) out[5000 + 10 * r + q] = 0.f;
      }
    }
  }
}

extern "C" void kernel_launch(void* const* d_in, const int* in_sizes, int n_in,
                              void* d_out, int out_size, void* d_ws, size_t ws_size,
                              hipStream_t stream) {
  const float* s8   = (const float*)d_in[1];
  const float* bb8  = (const float*)d_in[2];
  const float* kp8  = (const float*)d_in[3];
  const float* s16  = (const float*)d_in[4];
  const float* bb16 = (const float*)d_in[5];
  const float* kp16 = (const float*)d_in[6];
  const float* s32  = (const float*)d_in[7];
  const float* bb32 = (const float*)d_in[8];
  const float* kp32 = (const float*)d_in[9];

  char* ws = (char*)d_ws;
  u32* hist    = (u32*)(ws + OFF_HIST);
  u32* meta    = (u32*)(ws + OFF_META);
  u64* nzWords = (u64*)(ws + OFF_NZ);
  u64* list    = (u64*)(ws + OFF_LIST);
  u64* mask    = (u64*)(ws + OFF_MASK);

  hipMemsetAsync(ws, 0, MEMSET_BYTES, stream);
  k_mono<<<NBLK, 256, 0, stream>>>(s8, s16, s32, bb8, kp8, bb16, kp16, bb32, kp32,
                                   hist, meta, nzWords, list, mask, (float*)d_out);
}

// Round 6
// 211.413 us; speedup vs baseline: 1.4139x; 1.1130x over previous
//
#include <hip/hip_runtime.h>
#include <stdint.h>

typedef unsigned int u32;
typedef unsigned long long u64;

#define N8   130560   // (2176/8)*(3840/8)   = 272*480
#define N16  32640    // (2176/16)*(3840/16) = 136*240
#define N32  8160     // (2176/32)*(3840/32) = 68*120
#define NTOT 171360
#define NTOT4 42840   // NTOT/4
#define TOPK 1000
#define NWORDS 16
#define NBINS 4096
#define NREP 4             // histogram replicas (hot-line atomic contention / 4)
#define BUCKET_SCALE 682.0f
#define LIST_CAP 2048
#define NBLK 168           // ceil(NTOT4/256); <=256 CUs -> co-resident
#define IOU_TASKS (TOPK * NWORDS)   // 16000
#define IOU_BLKS 63
#define NMS_CACHE 256

// workspace layout (bytes)
#define OFF_HIST 0          // u32[NREP*4096] = 64 KB
#define OFF_META 65536      // u32[64]: [1]=listCnt; gbar ctrs [16],[32],[48]; E-arrive [56]
#define OFF_NZ   65792      // u64[16]
#define MEMSET_BYTES 65920
#define OFF_LIST 65920      // u64[2048]
#define OFF_MASK 82304      // u64[16*1000], transposed: mask[w*1000+i]

// ---- agent-scope relaxed atomics (sc1: bypass L1/L2, coherent at IF point). ----
// All data crossing a grid-sync uses these -> gbar needs NO threadfence (no wbl2/inv).
__device__ __forceinline__ u32 ald32(const u32* p) {
  return __hip_atomic_load(p, __ATOMIC_RELAXED, __HIP_MEMORY_SCOPE_AGENT);
}
__device__ __forceinline__ u64 ald64(const u64* p) {
  return __hip_atomic_load(p, __ATOMIC_RELAXED, __HIP_MEMORY_SCOPE_AGENT);
}
__device__ __forceinline__ void ast32(u32* p, u32 v) {
  __hip_atomic_store(p, v, __ATOMIC_RELAXED, __HIP_MEMORY_SCOPE_AGENT);
}
__device__ __forceinline__ void ast64(u64* p, u64 v) {
  __hip_atomic_store(p, v, __ATOMIC_RELAXED, __HIP_MEMORY_SCOPE_AGENT);
}
__device__ __forceinline__ u64 packf2(float a, float b) {
  return (u64)__float_as_uint(a) | ((u64)__float_as_uint(b) << 32);
}

__device__ __forceinline__ u32 bucket_of(float x) {
  u32 b = (u32)(x * BUCKET_SCALE);
  return b > (NBINS - 1) ? (NBINS - 1) : b;
}

__device__ __forceinline__ float4 load_logit4(int v, const float* s8, const float* s16,
                                              const float* s32) {
  int e = v * 4;
  if (e < N8) return ((const float4*)s8)[v];
  if (e < N8 + N16) return ((const float4*)s16)[v - N8 / 4];
  return ((const float4*)s32)[v - (N8 + N16) / 4];
}

__device__ __forceinline__ bool iou_gt04(float4 a, float4 b) {
#pragma clang fp contract(off)
  float areaA = (a.z - a.x) * (a.w - a.y);
  float areaB = (b.z - b.x) * (b.w - b.y);
  float ltx = fmaxf(a.x, b.x);
  float lty = fmaxf(a.y, b.y);
  float rbx = fminf(a.z, b.z);
  float rby = fminf(a.w, b.w);
  float wx = rbx - ltx; wx = wx > 0.0f ? wx : 0.0f;
  float wy = rby - lty; wy = wy > 0.0f ? wy : 0.0f;
  float inter = wx * wy;
  float un = areaA + areaB - inter;
  un = un > 1e-9f ? un : 1e-9f;
  return (inter / un) > 0.4f;
}

__device__ __forceinline__ u64 valid_word(int w, u32 vcnt) {
  int lo = w * 64;
  if ((int)vcnt >= lo + 64) return ~0ull;
  if ((int)vcnt <= lo) return 0ull;
  return (1ull << (vcnt - (u32)lo)) - 1ull;
}

// Fence-free grid barrier: __syncthreads drains vmcnt(0) (compiler-guaranteed before
// s_barrier), which makes all prior sc1 stores IF-visible; the arrive-RMW and the spin
// load are themselves sc1. Readers after the barrier use sc1 loads -> no stale cache.
// R4's all-thread fences (167us) and R5's t0 fences (~20us/barrier of wbl2/inv L2
// tag-walks) are both eliminated.
__device__ __forceinline__ void gbar(u32* ctr) {
  __syncthreads();
  if (threadIdx.x == 0) {
    __hip_atomic_fetch_add(ctr, 1u, __ATOMIC_RELAXED, __HIP_MEMORY_SCOPE_AGENT);
    while (__hip_atomic_load(ctr, __ATOMIC_RELAXED, __HIP_MEMORY_SCOPE_AGENT) < (u32)NBLK)
      __builtin_amdgcn_s_sleep(2);
  }
  __syncthreads();
}

__global__ void __launch_bounds__(256) k_mono(
    const float* __restrict__ s8, const float* __restrict__ s16, const float* __restrict__ s32,
    const float* __restrict__ bb8, const float* __restrict__ kp8,
    const float* __restrict__ bb16, const float* __restrict__ kp16,
    const float* __restrict__ bb32, const float* __restrict__ kp32,
    u32* hist, u32* meta, u64* nzWords, u64* list, u64* mask, float* out) {
  // phase-overlaid LDS: B(hloc+csum)=17.4K, D(keys)=16K, E(boxes)=16K, F(rows+cache)=36.9K
  __shared__ __align__(16) char smem[36864];
  __shared__ u32 sB;
  __shared__ int isLast;
  __shared__ u32 sPc[16], sOff17[17];
  __shared__ u64 sRem[NWORDS];

  const int t = threadIdx.x;
  const int blk = blockIdx.x;
  const int gid = blk * 256 + t;
  u64* out64 = (u64*)out;               // boxes: rows of 2 u64
  u64* outk64 = (u64*)(out + 5000);     // kps: rows of 5 u64 (byte 20000, 8B aligned)
  u32* outs32 = (u32*)(out + 4000);     // scores

  // ---- Phase A: replicated histogram of positive logits (scores stay in registers) ----
  float4 x = make_float4(-1.f, -1.f, -1.f, -1.f);
  const bool have = (gid < NTOT4);
  if (have) {
    u32* h = hist + (blk & (NREP - 1)) * NBINS;
    x = load_logit4(gid, s8, s16, s32);
    if (x.x > 0.0f) atomicAdd(&h[bucket_of(x.x)], 1u);
    if (x.y > 0.0f) atomicAdd(&h[bucket_of(x.y)], 1u);
    if (x.z > 0.0f) atomicAdd(&h[bucket_of(x.z)], 1u);
    if (x.w > 0.0f) atomicAdd(&h[bucket_of(x.w)], 1u);
  }
  gbar(&meta[16]);

  // ---- Phase B: findB, redundant per block ----
  // B = max bucket with count(>=B) >= TOPK; 0 if fewer than TOPK positives.
  {
    u32* hloc = (u32*)smem;             // 4096 u32
    u32* csum = (u32*)(smem + 16384);   // 256 u32
#pragma unroll
    for (int k = 0; k < 16; ++k) {      // sum replicas; independent sc1 loads, pipelined
      int b = k * 256 + t;
      u32 v = 0;
#pragma unroll
      for (int r = 0; r < NREP; ++r) v += ald32(&hist[r * NBINS + b]);
      hloc[b] = v;
    }
    __syncthreads();
    u32 sum = 0;
    int base = t * 16;
#pragma unroll
    for (int k = 0; k < 16; ++k) sum += hloc[base + k];
    csum[t] = sum;
    __syncthreads();
    for (int off = 1; off < 256; off <<= 1) {   // inclusive suffix scan
      u32 add = (t + off < 256) ? csum[t + off] : 0u;
      __syncthreads();
      csum[t] += add;
      __syncthreads();
    }
    if (t == 0 && csum[0] < TOPK) sB = 0;
    u32 above = (t < 255) ? csum[t + 1] : 0u;
    if (csum[t] >= TOPK && above < TOPK) {      // exactly one thread
      u32 cum = above, Bv = (u32)(t * 16);
      for (int b = t * 16 + 15; b >= t * 16; --b) {
        cum += hloc[b];
        if (cum >= TOPK) { Bv = (u32)b; break; }
      }
      sB = Bv;
    }
    __syncthreads();
  }
  const u32 B = sB;

  // ---- Phase C: compact candidates (bucket >= B) as (logit_bits<<32)|~idx ----
  if (have) {
    float c[4] = {x.x, x.y, x.z, x.w};
#pragma unroll
    for (int j = 0; j < 4; ++j) {
      float xx = c[j];
      if (xx > 0.0f && bucket_of(xx) >= B) {
        u32 pos = atomicAdd(&meta[1], 1u);
        if (pos < LIST_CAP) {
          u32 idx = (u32)(gid * 4 + j);
          ast64(&list[pos], ((u64)__float_as_uint(xx) << 32) | (u64)(~idx));
        }
      }
    }
  }
  gbar(&meta[32]);

  u32 cnt = ald32(&meta[1]);
  if (cnt > LIST_CAP) cnt = LIST_CAP;
  const u32 vcnt = cnt < TOPK ? cnt : TOPK;   // all selected have logit>0 => valid

  // ---- Phase D: O(n^2) exact rank (desc key = stable top-k) + decode -> out, blocks 0..7 ----
  if (blk < 8) {
    u64* keys = (u64*)smem;
    for (int j = t; j < LIST_CAP; j += 256) keys[j] = (j < (int)cnt) ? ald64(&list[j]) : 0ull;
    __syncthreads();
    int tid = blk * 256 + t;
    if (tid < (int)cnt) {
      u64 my = keys[tid];
      int rank = 0, j = 0;
      for (; j + 4 <= (int)cnt; j += 4)
        rank += (keys[j] > my) + (keys[j + 1] > my) + (keys[j + 2] > my) + (keys[j + 3] > my);
      for (; j < (int)cnt; ++j) rank += (keys[j] > my);
      if (rank < TOPK) {
        float lx = __uint_as_float((u32)(my >> 32));
        float sc = (float)(1.0 / (1.0 + exp(-(double)lx)));   // sigmoid in f64, round once
        u32 idx = ~((u32)my);
        float bx, by, bz, bw;
        float kv[10];
        int p, xq, yq;
        float st;
        const float *bb, *kp;
        if (idx < N8) {
          st = 8.f;  p = (int)idx;              xq = p % 480; yq = p / 480; bb = bb8;  kp = kp8;
        } else if (idx < N8 + N16) {
          st = 16.f; p = (int)idx - N8;         xq = p % 240; yq = p / 240; bb = bb16; kp = kp16;
        } else {
          st = 32.f; p = (int)idx - (N8 + N16); xq = p % 120; yq = p / 120; bb = bb32; kp = kp32;
        }
        float cx = (float)xq * st, cy = (float)yq * st;
        {
#pragma clang fp contract(off)
          float d0 = bb[4 * p + 0] * st;
          float d1 = bb[4 * p + 1] * st;
          float d2 = bb[4 * p + 2] * st;
          float d3 = bb[4 * p + 3] * st;
          bx = cx - d0; by = cy - d1; bz = cx + d2; bw = cy + d3;
          for (int q = 0; q < 10; ++q)
            kv[q] = kp[10 * p + q] * st + ((q & 1) ? cy : cx);
        }
        ast64(&out64[2 * rank], packf2(bx, by));
        ast64(&out64[2 * rank + 1], packf2(bz, bw));
        ast32(&outs32[rank], __float_as_uint(sc));
#pragma unroll
        for (int q = 0; q < 5; ++q)
          ast64(&outk64[5 * rank + q], packf2(kv[2 * q], kv[2 * q + 1]));
      }
    } else if (tid < TOPK) {   // unfilled rows: zero
      ast64(&out64[2 * tid], 0ull);
      ast64(&out64[2 * tid + 1], 0ull);
      ast32(&outs32[tid], 0u);
#pragma unroll
      for (int q = 0; q < 5; ++q) ast64(&outk64[5 * tid + q], 0ull);
    }
  }
  gbar(&meta[48]);

  // ---- Phase E: suppression bitmask + nz bitmap, blocks 0..62 ----
  if (blk < IOU_BLKS) {
    float4* boxes = (float4*)smem;
    for (int r = t; r < TOPK; r += 256) {
      u64 a0 = ald64(&out64[2 * r]);
      u64 a1 = ald64(&out64[2 * r + 1]);
      boxes[r] = make_float4(__uint_as_float((u32)a0), __uint_as_float((u32)(a0 >> 32)),
                             __uint_as_float((u32)a1), __uint_as_float((u32)(a1 >> 32)));
    }
    __syncthreads();
    int task = blk * 256 + t;
    if (task < IOU_TASKS) {
      int w = task / 1000;          // 0..15  (wave-mostly-uniform)
      int i = task - w * 1000;      // 0..999 (consecutive per lane -> coalesced)
      float4 a = boxes[i];
      int bse = w * 64;
      int jend = (bse + 64) < TOPK ? (bse + 64) : TOPK;
      u64 bits = 0;
      for (int j = bse; j < jend; ++j)          // boxes[j] wave-broadcast, conflict-free
        if (j > i && iou_gt04(a, boxes[j])) bits |= 1ull << (j - bse);
      ast64(&mask[(u64)w * 1000 + i], bits);    // coalesced (transposed layout)
      if (bits) atomicOr(&nzWords[i >> 6], 1ull << (i & 63));
    }
    // last-arriver of the 63 IOU blocks runs NMS + suppressed-row zeroing (fence-free:
    // __syncthreads drains vmcnt -> sc1 stores visible; reads below are sc1)
    __syncthreads();
    if (t == 0)
      isLast = (__hip_atomic_fetch_add(&meta[56], 1u, __ATOMIC_RELAXED,
                                       __HIP_MEMORY_SCOPE_AGENT) == (u32)(IOU_BLKS - 1));
    __syncthreads();
    if (!isLast) return;

    // ---- Phase F: exact greedy NMS over nonzero-mask rows only ----
    // Rows with empty suppression sets can't change the removed set -> skipping is exact.
    u32* rows = (u32*)smem;             // up to 1000 row ids (4 KB)
    u64* cache = (u64*)(smem + 4096);   // NMS_CACHE x 16 u64 (32 KB)
    u64 nzv = 0;
    if (t < NWORDS) {
      nzv = ald64(&nzWords[t]) & valid_word(t, vcnt);
      sPc[t] = (u32)__popcll(nzv);
    }
    __syncthreads();
    if (t == 0) {
      u32 o = 0;
      for (int w = 0; w < NWORDS; ++w) { sOff17[w] = o; o += sPc[w]; }
      sOff17[16] = o;
    }
    __syncthreads();
    if (t < NWORDS) {           // expand to ascending row list
      u64 m = nzv;
      u32 o = sOff17[t];
      while (m) { int b = __builtin_ctzll(m); m &= m - 1; rows[o++] = (u32)(t * 64 + b); }
    }
    __syncthreads();
    const int S = (int)sOff17[16];
    const int Sc = S < NMS_CACHE ? S : NMS_CACHE;
    for (int idx = t; idx < Sc * NWORDS; idx += 256) {   // parallel mask prefetch -> LDS
      int s = idx >> 4, w = idx & 15;
      cache[s * NWORDS + w] = ald64(&mask[(u64)w * 1000 + rows[s]]);
    }
    __syncthreads();
    if (t < 64) {               // serial greedy chain, LDS-fed; lane<16 owns word `lane`
      u64 remv = 0;
      for (int s = 0; s < S; ++s) {
        u32 row = rows[s];
        int c = (int)(row >> 6), b = (int)(row & 63);
        u64 remc = __shfl(remv, c);
        if (!((remc >> b) & 1ull)) {   // row still alive -> apply its suppression row
          u64 m = 0;
          if (t < NWORDS)
            m = (s < NMS_CACHE) ? cache[s * NWORDS + t] : ald64(&mask[(u64)t * 1000 + row]);
          remv |= m;
        }
      }
      if (t < NWORDS) sRem[t] = valid_word(t, vcnt) & remv;   // rows to zero
    }
    __syncthreads();

    // ---- zero suppressed rows in out (sc1 stores: win over D's sc1 stores at IF) ----
    for (int r = t; r < TOPK; r += 256) {
      if ((sRem[r >> 6] >> (r & 63)) & 1ull) {
        ast64(&out64[2 * r], 0ull);
        ast64(&out64[2 * r + 1], 0ull);
        ast32(&outs32[r], 0u);
#pragma unroll
        for (int q = 0; q < 5; ++q) ast64(&outk64[5 * r + q], 0ull);
      }
    }
  }
}

extern "C" void kernel_launch(void* const* d_in, const int* in_sizes, int n_in,
                              void* d_out, int out_size, void* d_ws, size_t ws_size,
                              hipStream_t stream) {
  const float* s8   = (const float*)d_in[1];
  const float* bb8  = (const float*)d_in[2];
  const float* kp8  = (const float*)d_in[3];
  const float* s16  = (const float*)d_in[4];
  const float* bb16 = (const float*)d_in[5];
  const float* kp16 = (const float*)d_in[6];
  const float* s32  = (const float*)d_in[7];
  const float* bb32 = (const float*)d_in[8];
  const float* kp32 = (const float*)d_in[9];

  char* ws = (char*)d_ws;
  u32* hist    = (u32*)(ws + OFF_HIST);
  u32* meta    = (u32*)(ws + OFF_META);
  u64* nzWords = (u64*)(ws + OFF_NZ);
  u64* list    = (u64*)(ws + OFF_LIST);
  u64* mask    = (u64*)(ws + OFF_MASK);

  hipMemsetAsync(ws, 0, MEMSET_BYTES, stream);
  k_mono<<<NBLK, 256, 0, stream>>>(s8, s16, s32, bb8, kp8, bb16, kp16, bb32, kp32,
                                   hist, meta, nzWords, list, mask, (float*)d_out);
}

// Round 7
// 205.477 us; speedup vs baseline: 1.4547x; 1.0289x over previous
//
#include <hip/hip_runtime.h>
#include <stdint.h>

typedef unsigned int u32;
typedef unsigned long long u64;

#define N8   130560   // (2176/8)*(3840/8)   = 272*480
#define N16  32640    // (2176/16)*(3840/16) = 136*240
#define N32  8160     // (2176/32)*(3840/32) = 68*120
#define NTOT 171360
#define NTOT4 42840   // NTOT/4
#define TOPK 1000
#define NWORDS 16
#define NBINS 4096
#define NREP 4             // histogram replicas (hot-line atomic contention / 4)
#define BUCKET_SCALE 682.0f
#define LIST_CAP 2048
#define NBLK 168           // ceil(NTOT4/256)
#define IOU_TASKS (TOPK * NWORDS)   // 16000
#define IOU_BLKS 63
#define NMS_CACHE 256

// workspace layout (bytes)
#define OFF_HIST 0          // u32[NREP*4096] = 64 KB
#define OFF_META 65536      // u32[64]: [1]=listCnt; [56]=E-arrive ctr
#define OFF_NZ   65792      // u64[16]
#define MEMSET_BYTES 65920
#define OFF_LIST 65920      // u64[2048]
#define OFF_MASK 82304      // u64[16*1000], transposed: mask[w*1000+i]

// sc1 helpers (agent-scope relaxed; L1/L2-bypass) — used ONLY for the E->F
// last-arriver handoff inside k_iou_nms. Everything else is plain-cached:
// dispatch boundaries provide release/acquire coherence between kernels.
__device__ __forceinline__ u64 ald64(const u64* p) {
  return __hip_atomic_load(p, __ATOMIC_RELAXED, __HIP_MEMORY_SCOPE_AGENT);
}
__device__ __forceinline__ void ast64(u64* p, u64 v) {
  __hip_atomic_store(p, v, __ATOMIC_RELAXED, __HIP_MEMORY_SCOPE_AGENT);
}

__device__ __forceinline__ u32 bucket_of(float x) {
  u32 b = (u32)(x * BUCKET_SCALE);
  return b > (NBINS - 1) ? (NBINS - 1) : b;
}

__device__ __forceinline__ float4 load_logit4(int v, const float* s8, const float* s16,
                                              const float* s32) {
  int e = v * 4;
  if (e < N8) return ((const float4*)s8)[v];
  if (e < N8 + N16) return ((const float4*)s16)[v - N8 / 4];
  return ((const float4*)s32)[v - (N8 + N16) / 4];
}

__device__ __forceinline__ bool iou_gt04(float4 a, float4 b) {
#pragma clang fp contract(off)
  float areaA = (a.z - a.x) * (a.w - a.y);
  float areaB = (b.z - b.x) * (b.w - b.y);
  float ltx = fmaxf(a.x, b.x);
  float lty = fmaxf(a.y, b.y);
  float rbx = fminf(a.z, b.z);
  float rby = fminf(a.w, b.w);
  float wx = rbx - ltx; wx = wx > 0.0f ? wx : 0.0f;
  float wy = rby - lty; wy = wy > 0.0f ? wy : 0.0f;
  float inter = wx * wy;
  float un = areaA + areaB - inter;
  un = un > 1e-9f ? un : 1e-9f;
  return (inter / un) > 0.4f;
}

__device__ __forceinline__ u64 valid_word(int w, u32 vcnt) {
  int lo = w * 64;
  if ((int)vcnt >= lo + 64) return ~0ull;
  if ((int)vcnt <= lo) return 0ull;
  return (1ull << (vcnt - (u32)lo)) - 1ull;
}

// K1: replicated histogram of positive logits (plain cached atomics)
__global__ void __launch_bounds__(256) k_hist(
    const float* __restrict__ s8, const float* __restrict__ s16, const float* __restrict__ s32,
    u32* __restrict__ hist) {
  int v = blockIdx.x * 256 + threadIdx.x;
  if (v >= NTOT4) return;
  u32* h = hist + (blockIdx.x & (NREP - 1)) * NBINS;
  float4 x = load_logit4(v, s8, s16, s32);
  if (x.x > 0.0f) atomicAdd(&h[bucket_of(x.x)], 1u);
  if (x.y > 0.0f) atomicAdd(&h[bucket_of(x.y)], 1u);
  if (x.z > 0.0f) atomicAdd(&h[bucket_of(x.z)], 1u);
  if (x.w > 0.0f) atomicAdd(&h[bucket_of(x.w)], 1u);
}

// K2: per-block redundant findB (cached hist reads) + compact.
// B = max bucket with count(>=B) >= TOPK; 0 if fewer than TOPK positives.
__global__ void __launch_bounds__(256) k_findB_compact(
    const float* __restrict__ s8, const float* __restrict__ s16, const float* __restrict__ s32,
    const u32* __restrict__ hist, u32* __restrict__ meta, u64* __restrict__ list) {
  __shared__ u32 hloc[NBINS];
  __shared__ u32 csum[256];
  __shared__ u32 sB;
  int t = threadIdx.x;
#pragma unroll
  for (int k = 0; k < 16; ++k) {
    int b = k * 256 + t;
    u32 v = 0;
#pragma unroll
    for (int r = 0; r < NREP; ++r) v += hist[r * NBINS + b];
    hloc[b] = v;
  }
  __syncthreads();
  u32 sum = 0;
  int base = t * 16;
#pragma unroll
  for (int k = 0; k < 16; ++k) sum += hloc[base + k];
  csum[t] = sum;
  __syncthreads();
  for (int off = 1; off < 256; off <<= 1) {   // inclusive suffix scan
    u32 add = (t + off < 256) ? csum[t + off] : 0u;
    __syncthreads();
    csum[t] += add;
    __syncthreads();
  }
  if (t == 0 && csum[0] < TOPK) sB = 0;
  u32 above = (t < 255) ? csum[t + 1] : 0u;
  if (csum[t] >= TOPK && above < TOPK) {      // exactly one thread
    u32 cum = above, Bv = (u32)(t * 16);
    for (int b = t * 16 + 15; b >= t * 16; --b) {
      cum += hloc[b];
      if (cum >= TOPK) { Bv = (u32)b; break; }
    }
    sB = Bv;
  }
  __syncthreads();
  const u32 B = sB;

  int v = blockIdx.x * 256 + t;
  if (v >= NTOT4) return;
  float4 x = load_logit4(v, s8, s16, s32);
  float c[4] = {x.x, x.y, x.z, x.w};
#pragma unroll
  for (int j = 0; j < 4; ++j) {
    float xx = c[j];
    if (xx > 0.0f && bucket_of(xx) >= B) {
      u32 pos = atomicAdd(&meta[1], 1u);
      if (pos < LIST_CAP) {
        u32 idx = (u32)(v * 4 + j);
        list[pos] = ((u64)__float_as_uint(xx) << 32) | (u64)(~idx);
      }
    }
  }
}

// K3: O(n^2) exact rank (desc key = stable top-k) + decode -> out, 8 blocks.
// out layout: [boxes 4000 | scores 1000 | kps 10000]; rows [cnt,1000) zeroed here.
__global__ void __launch_bounds__(256) k_rank_decode(
    const u64* __restrict__ list, const u32* __restrict__ meta,
    const float* __restrict__ bb8,  const float* __restrict__ kp8,
    const float* __restrict__ bb16, const float* __restrict__ kp16,
    const float* __restrict__ bb32, const float* __restrict__ kp32,
    float* __restrict__ out) {
  __shared__ u64 keys[LIST_CAP];
  int t = threadIdx.x;
  u32 cnt = meta[1];
  if (cnt > LIST_CAP) cnt = LIST_CAP;
  for (int j = t; j < LIST_CAP; j += 256) keys[j] = (j < (int)cnt) ? list[j] : 0ull;
  __syncthreads();
  int tid = blockIdx.x * 256 + t;
  if (tid < (int)cnt) {
    u64 my = keys[tid];
    int rank = 0, j = 0;
    for (; j + 4 <= (int)cnt; j += 4)
      rank += (keys[j] > my) + (keys[j + 1] > my) + (keys[j + 2] > my) + (keys[j + 3] > my);
    for (; j < (int)cnt; ++j) rank += (keys[j] > my);
    if (rank < TOPK) {
      float lx = __uint_as_float((u32)(my >> 32));
      float sc = (float)(1.0 / (1.0 + exp(-(double)lx)));   // sigmoid in f64, round once
      u32 idx = ~((u32)my);
      float4 box;
      float kv[10];
      int p, xq, yq;
      float st;
      const float *bb, *kp;
      if (idx < N8) {
        st = 8.f;  p = (int)idx;              xq = p % 480; yq = p / 480; bb = bb8;  kp = kp8;
      } else if (idx < N8 + N16) {
        st = 16.f; p = (int)idx - N8;         xq = p % 240; yq = p / 240; bb = bb16; kp = kp16;
      } else {
        st = 32.f; p = (int)idx - (N8 + N16); xq = p % 120; yq = p / 120; bb = bb32; kp = kp32;
      }
      float cx = (float)xq * st, cy = (float)yq * st;
      {
#pragma clang fp contract(off)
        float d0 = bb[4 * p + 0] * st;
        float d1 = bb[4 * p + 1] * st;
        float d2 = bb[4 * p + 2] * st;
        float d3 = bb[4 * p + 3] * st;
        box.x = cx - d0; box.y = cy - d1; box.z = cx + d2; box.w = cy + d3;
        for (int q = 0; q < 10; ++q)
          kv[q] = kp[10 * p + q] * st + ((q & 1) ? cy : cx);
      }
      ((float4*)out)[rank] = box;
      out[4000 + rank] = sc;
      for (int q = 0; q < 10; ++q) out[5000 + 10 * rank + q] = kv[q];
    }
  } else if (tid < TOPK) {   // unfilled rows: zero
    ((float4*)out)[tid] = make_float4(0.f, 0.f, 0.f, 0.f);
    out[4000 + tid] = 0.f;
    for (int q = 0; q < 10; ++q) out[5000 + 10 * tid + q] = 0.f;
  }
}

// K4: suppression bitmask (63 blocks) + last-arriver greedy NMS + suppressed-row zeroing.
// mask/nz cross blocks within this dispatch -> sc1 stores + fence-free last-arriver
// (syncthreads drains vmcnt; sc1 ops are IF-coherent). Box reads are plain (from K3).
__global__ void __launch_bounds__(256) k_iou_nms(
    const u32* __restrict__ meta_ro, u32* meta, u64* nzWords, u64* mask, float* out) {
  __shared__ __align__(16) char smem[36864];
  __shared__ int isLast;
  __shared__ u32 sPc[16], sOff17[17];
  __shared__ u64 sRem[NWORDS];
  int t = threadIdx.x;
  int blk = blockIdx.x;

  float4* boxes = (float4*)smem;
  for (int r = t; r < TOPK; r += 256) boxes[r] = ((const float4*)out)[r];
  __syncthreads();
  int task = blk * 256 + t;
  if (task < IOU_TASKS) {
    int w = task / 1000;          // 0..15  (wave-mostly-uniform)
    int i = task - w * 1000;      // 0..999 (consecutive per lane -> coalesced)
    float4 a = boxes[i];
    int bse = w * 64;
    int jend = (bse + 64) < TOPK ? (bse + 64) : TOPK;
    u64 bits = 0;
    for (int j = bse; j < jend; ++j)          // boxes[j] wave-broadcast, conflict-free
      if (j > i && iou_gt04(a, boxes[j])) bits |= 1ull << (j - bse);
    ast64(&mask[(u64)w * 1000 + i], bits);    // coalesced (transposed layout)
    if (bits) atomicOr(&nzWords[i >> 6], 1ull << (i & 63));
  }
  __syncthreads();
  if (t == 0)
    isLast = (__hip_atomic_fetch_add(&meta[56], 1u, __ATOMIC_RELAXED,
                                     __HIP_MEMORY_SCOPE_AGENT) == (u32)(IOU_BLKS - 1));
  __syncthreads();
  if (!isLast) return;

  // ---- last arriver: exact greedy NMS over nonzero-mask rows only ----
  u32 cnt = meta_ro[1];
  if (cnt > LIST_CAP) cnt = LIST_CAP;
  const u32 vcnt = cnt < TOPK ? cnt : TOPK;
  u32* rows = (u32*)smem;             // up to 1000 row ids (4 KB)
  u64* cache = (u64*)(smem + 4096);   // NMS_CACHE x 16 u64 (32 KB)
  u64 nzv = 0;
  if (t < NWORDS) {
    nzv = ald64(&nzWords[t]) & valid_word(t, vcnt);
    sPc[t] = (u32)__popcll(nzv);
  }
  __syncthreads();
  if (t == 0) {
    u32 o = 0;
    for (int w = 0; w < NWORDS; ++w) { sOff17[w] = o; o += sPc[w]; }
    sOff17[16] = o;
  }
  __syncthreads();
  if (t < NWORDS) {           // expand to ascending row list
    u64 m = nzv;
    u32 o = sOff17[t];
    while (m) { int b = __builtin_ctzll(m); m &= m - 1; rows[o++] = (u32)(t * 64 + b); }
  }
  __syncthreads();
  const int S = (int)sOff17[16];
  const int Sc = S < NMS_CACHE ? S : NMS_CACHE;
  for (int idx = t; idx < Sc * NWORDS; idx += 256) {   // parallel mask prefetch -> LDS
    int s = idx >> 4, w = idx & 15;
    cache[s * NWORDS + w] = ald64(&mask[(u64)w * 1000 + rows[s]]);
  }
  __syncthreads();
  if (t < 64) {               // serial greedy chain, LDS-fed; lane<16 owns word `lane`
    u64 remv = 0;
    for (int s = 0; s < S; ++s) {
      u32 row = rows[s];
      int c = (int)(row >> 6), b = (int)(row & 63);
      u64 remc = __shfl(remv, c);
      if (!((remc >> b) & 1ull)) {   // row still alive -> apply its suppression row
        u64 m = 0;
        if (t < NWORDS)
          m = (s < NMS_CACHE) ? cache[s * NWORDS + t] : ald64(&mask[(u64)t * 1000 + row]);
        remv |= m;
      }
    }
    if (t < NWORDS) sRem[t] = valid_word(t, vcnt) & remv;   // rows to zero
  }
  __syncthreads();
  for (int r = t; r < TOPK; r += 256) {
    if ((sRem[r >> 6] >> (r & 63)) & 1ull) {
      ((float4*)out)[r] = make_float4(0.f, 0.f, 0.f, 0.f);
      out[4000 + r] = 0.f;
      for (int q = 0; q < 10; ++q) out[5000 + 10 * r + q] = 0.f;
    }
  }
}

extern "C" void kernel_launch(void* const* d_in, const int* in_sizes, int n_in,
                              void* d_out, int out_size, void* d_ws, size_t ws_size,
                              hipStream_t stream) {
  const float* s8   = (const float*)d_in[1];
  const float* bb8  = (const float*)d_in[2];
  const float* kp8  = (const float*)d_in[3];
  const float* s16  = (const float*)d_in[4];
  const float* bb16 = (const float*)d_in[5];
  const float* kp16 = (const float*)d_in[6];
  const float* s32  = (const float*)d_in[7];
  const float* bb32 = (const float*)d_in[8];
  const float* kp32 = (const float*)d_in[9];

  char* ws = (char*)d_ws;
  u32* hist    = (u32*)(ws + OFF_HIST);
  u32* meta    = (u32*)(ws + OFF_META);
  u64* nzWords = (u64*)(ws + OFF_NZ);
  u64* list    = (u64*)(ws + OFF_LIST);
  u64* mask    = (u64*)(ws + OFF_MASK);
  float* out   = (float*)d_out;

  hipMemsetAsync(ws, 0, MEMSET_BYTES, stream);
  k_hist<<<NBLK, 256, 0, stream>>>(s8, s16, s32, hist);
  k_findB_compact<<<NBLK, 256, 0, stream>>>(s8, s16, s32, hist, meta, list);
  k_rank_decode<<<8, 256, 0, stream>>>(list, meta, bb8, kp8, bb16, kp16, bb32, kp32, out);
  k_iou_nms<<<IOU_BLKS, 256, 0, stream>>>(meta, meta, nzWords, mask, out);
}